// Round 3
// baseline (594.170 us; speedup 1.0000x reference)
//
#include <hip/hip_runtime.h>

// NormXCorr: B=16, D=64, H=48, W=24, p=5, d=2, n=25, EPS=0.01
// out[b, d*120 + a*24 + c, x, y] = mean_k En[b,d,x,y,k] * Fn[b,d,x+a,c,k]
// Algebra: sum_k En_k = 0 exactly, so ncc = (0.04*invX*invY) * sum_k (X_k-muX) * Y_k
//
// R3 change: SEQUENTIAL WRITE STREAM. Theory: kernel portion (~224 us) is
// dominated by HBM write inefficiency -- old pattern wrote scattered 256 B
// chunks at 4.6 KB stride (120 chunks over 550 KB per wave). Fill kernel
// proves 6.2 TB/s for sequential streams. New structure: block = one (b,d)
// slice, 384 threads = 48 x * 8 ygroups, thread owns 3 consecutive y.
// Loops: a outer, c inner -> per c-step the whole block stores the full
// contiguous 4.6 KB output plane (dwordx3 per lane, lanes contiguous), and
// consecutive c-steps hit adjacent planes: each block writes its 553 KB
// output slice front-to-back sequentially.

#define BH 48
#define BW 24
constexpr float EPS = 0.01f;

#define XPS 29   // Xp row stride   : Xp[row*29 + col],    row 0..51, col 0..27
#define YTS 57   // YpT col stride  : YpT[col*57 + row],   col 0..27, row 0..55
#define IVS 53   // invYT stride    : invYT[col*53 + row], col 0..23, row 0..51

__global__ __launch_bounds__(384, 4) void ncc_kernel(const float* __restrict__ X,
                                                     const float* __restrict__ Y,
                                                     float* __restrict__ out) {
    __shared__ float Xp[52 * XPS];      // X padded +2 all sides (row-major)
    __shared__ float YpT[28 * YTS];     // Y padded +4 vert +2 horiz (TRANSPOSED)
    __shared__ float invYT[24 * IVS];   // 1/(sd+eps) per Y patch pos (transposed)

    const int bd  = blockIdx.x;        // b*64 + d, 0..1023
    const int tid = threadIdx.x;       // 0..383

    const float* Xg = X + (size_t)bd * (BH * BW);
    const float* Yg = Y + (size_t)bd * (BH * BW);

    // ---- stage padded X slice (row-major, stride 29) ----
    for (int i = tid; i < 52 * 28; i += 384) {
        int r = i / 28, c = i % 28;
        int orr = r - 2, oc = c - 2;
        float v = 0.f;
        if (orr >= 0 && orr < BH && oc >= 0 && oc < BW) v = Xg[orr * BW + oc];
        Xp[r * XPS + c] = v;
    }
    // ---- stage padded Y slice transposed: YpT[col][row] ----
    for (int i = tid; i < 56 * 28; i += 384) {
        int r = i / 28, c = i % 28;
        int orr = r - 4, oc = c - 2;
        float v = 0.f;
        if (orr >= 0 && orr < BH && oc >= 0 && oc < BW) v = Yg[orr * BW + oc];
        YpT[c * YTS + r] = v;
    }
    __syncthreads();

    // ---- Y patch inverse-std for all 52x24 patch positions (transposed) ----
    for (int i = tid; i < 52 * 24; i += 384) {
        int c = i % 24, r = i / 24;
        float s = 0.f, s2 = 0.f;
#pragma unroll
        for (int v = 0; v < 5; ++v)
#pragma unroll
            for (int u = 0; u < 5; ++u) {
                float val = YpT[(c + v) * YTS + (r + u)];
                s += val;
                s2 += val * val;
            }
        float mu  = s * 0.04f;
        float var = fmaxf(s2 * 0.04f - mu * mu, 0.f);
        invYT[c * IVS + r] = 1.f / (sqrtf(var) + EPS);
    }
    __syncthreads();

    // ---- main: thread = (x, ygroup of 3). All 1152 (x,y) in flight. ----
    const int x  = tid >> 3;        // 0..47
    const int y0 = (tid & 7) * 3;   // 0,3,...,21

    // X patches -> registers, normalized, pre-scaled by 0.04*invX
    float xn[3][25];
#pragma unroll
    for (int j = 0; j < 3; ++j) {
        float s = 0.f, s2 = 0.f;
#pragma unroll
        for (int u = 0; u < 5; ++u)
#pragma unroll
            for (int v = 0; v < 5; ++v) {
                float val = Xp[(x + u) * XPS + (y0 + j + v)];
                xn[j][u * 5 + v] = val;
                s += val;
                s2 += val * val;
            }
        float mu  = s * 0.04f;
        float var = fmaxf(s2 * 0.04f - mu * mu, 0.f);
        float sc  = 0.04f / (sqrtf(var) + EPS);
#pragma unroll
        for (int k = 0; k < 25; ++k) xn[j][k] = (xn[j][k] - mu) * sc;
    }

    // store pointer: plane (a*24+c), element x*24+y0 = 3*tid.
    // lanes contiguous (addr = 3*tid) -> per-wave 768 B contiguous dwordx3;
    // block covers the full 4.6 KB plane per c-step; planes visited in
    // memory order -> sequential 553 KB stream per block.
    float* op = out + (size_t)bd * (5 * 24 * 48 * 24) + 3 * tid;

#pragma unroll 1
    for (int a = 0; a < 5; ++a) {
        const int yr = x + a;   // Y patch row for this (x,a): 0..51

        // 5x5 ring window over Y columns; slot sl holds col c' with c'%5==sl.
        float w[5][5];
#pragma unroll
        for (int v = 0; v < 5; ++v)
#pragma unroll
            for (int u = 0; u < 5; ++u)
                w[v][u] = YpT[v * YTS + (yr + u)];

#pragma unroll
        for (int c = 0; c < 24; ++c) {
            float d0 = 0.f, d1 = 0.f, d2 = 0.f;
#pragma unroll
            for (int u = 0; u < 5; ++u)
#pragma unroll
                for (int v = 0; v < 5; ++v) {
                    const float f = w[(c + v) % 5][u];  // compile-time slot
                    d0 += xn[0][u * 5 + v] * f;
                    d1 += xn[1][u * 5 + v] * f;
                    d2 += xn[2][u * 5 + v] * f;
                }
            const float iv = invYT[c * IVS + yr];
            op[0] = d0 * iv;
            op[1] = d1 * iv;
            op[2] = d2 * iv;
            op += 48 * 24;   // next (a,c) plane: adjacent 4.6 KB in memory
            if (c < 23) {
                // slide: load column c+5 into the slot just freed (c%5)
#pragma unroll
                for (int u = 0; u < 5; ++u)
                    w[c % 5][u] = YpT[(c + 5) * YTS + (yr + u)];
            }
        }
    }
}

extern "C" void kernel_launch(void* const* d_in, const int* in_sizes, int n_in,
                              void* d_out, int out_size, void* d_ws, size_t ws_size,
                              hipStream_t stream) {
    const float* X = (const float*)d_in[0];
    const float* Y = (const float*)d_in[1];
    float* out = (float*)d_out;
    // d_in[2] is patch_size == 5, hardcoded above.
    ncc_kernel<<<dim3(1024), dim3(384), 0, stream>>>(X, Y, out);
}